// Round 3
// baseline (157.711 us; speedup 1.0000x reference)
//
#include <hip/hip_runtime.h>

// d_ws layout: 3408 x uint2 (half4 each): lo = half2(cos,sin) [for X-dot],
//                                         hi = half2(cos,-sin) [for Y-dot]
// [0..15]     conv1 (o*4 + dy*2 + dx)
// [16..527]   conv2 (o*64 + c*16 + dy*4 + dx)
// [528..3407] ff    (f*10 + n)
#define WT_W1 0
#define WT_W2 16
#define WT_FF 528

typedef _Float16 h2 __attribute__((ext_vector_type(2)));

__device__ __forceinline__ float fdot2(unsigned a, unsigned b, float c) {
    return __builtin_amdgcn_fdot2(__builtin_bit_cast(h2, a),
                                  __builtin_bit_cast(h2, b), c, false);
}
__device__ __forceinline__ unsigned swap16(unsigned v) {
    return (v >> 16) | (v << 16);   // v_alignbit_b32
}
__device__ __forceinline__ unsigned packh2(float x, float y) {
    h2 h; h.x = (_Float16)x; h.y = (_Float16)y;
    return __builtin_bit_cast(unsigned, h);
}

__global__ void ringnn_setup(const float* __restrict__ w1,
                             const float* __restrict__ w2,
                             const float* __restrict__ ffw,
                             uint2* __restrict__ wt) {
    int t = blockIdx.x * blockDim.x + threadIdx.x;
    if (t >= 3408) return;
    float a;
    if (t < 16)        a = w1[t];
    else if (t < 528)  a = w2[t - 16];
    else               a = ffw[t - 528];
    float s, c;
    __sincosf(a, &s, &c);
    uint2 v;
    v.x = packh2(c, s);
    v.y = packh2(c, -s);
    wt[t] = v;
}

// 256 threads = 4 waves; 2 images per block, 2 waves (128 lanes) per image.
__global__ __launch_bounds__(256, 8) void ringnn_main(
    const float* __restrict__ x,
    const uint2* __restrict__ wt,
    float* __restrict__ out)
{
    __shared__ uint2 w1t[16];
    // conv2 weights, PADDED: uint4 index = o*33 + c*8 + dy*2 + half
    // o-stride 33 uint4 = 132 words == 4 mod 32 -> the 8 o-groups tile all
    // 32 banks (bank conflict was 52% of cycles in R2 with stride 32).
    __shared__ uint4 w2t[264];
    __shared__ unsigned cs1[2][784];        // [img][c*196 + i*14 + j], half2
    __shared__ unsigned cs2[2][288];        // [img][(i*6+j)*8 + o], half2

    const int t   = threadIdx.x;
    const int img = t >> 7;                 // 0..1
    const int tid = t & 127;                // lane within the image's 2 waves
    const int b   = blockIdx.x * 2 + img;
    const float* xb = x + b * 784;

    // ---- Load weight tables into LDS (block-cooperative) ----
    for (int k = t; k < 528; k += 256) {
        uint2 val = wt[k];
        if (k < 16) {
            w1t[k] = val;
        } else {
            int kk = k - 16;
            int o = kk >> 6, rest = kk & 63;
            ((uint2*)w2t)[o * 66 + rest] = val;   // 66 = 33 uint4 per o
        }
    }
    __syncthreads();

    // ---- Stage 1: sincos from global + 2x2/s2 conv, 1->4 ch ----
    for (int pos = tid; pos < 196; pos += 128) {
        const int i = pos / 14;
        const int j = pos - i * 14;
        const float* px = xb + (2 * i) * 28 + 2 * j;
        float2 p0 = *(const float2*)(px);
        float2 p1 = *(const float2*)(px + 28);
        float s0, c0, s1, c1, s2, c2, s3, c3;
        __sincosf(p0.x, &s0, &c0);
        __sincosf(p0.y, &s1, &c1);
        __sincosf(p1.x, &s2, &c2);
        __sincosf(p1.y, &s3, &c3);
        unsigned v0 = packh2(c0, s0), v1 = packh2(c1, s1);
        unsigned v2 = packh2(c2, s2), v3 = packh2(c3, s3);
        unsigned sv0 = swap16(v0), sv1 = swap16(v1);
        unsigned sv2 = swap16(v2), sv3 = swap16(v3);
        #pragma unroll
        for (int o = 0; o < 4; ++o) {
            uint2 wa = w1t[o * 4 + 0], wb = w1t[o * 4 + 1];
            uint2 wc = w1t[o * 4 + 2], wd = w1t[o * 4 + 3];
            float X = 0.f, Y = 0.f;
            X = fdot2(v0, wa.x, X); Y = fdot2(sv0, wa.y, Y);
            X = fdot2(v1, wb.x, X); Y = fdot2(sv1, wb.y, Y);
            X = fdot2(v2, wc.x, X); Y = fdot2(sv2, wc.y, Y);
            X = fdot2(v3, wd.x, X); Y = fdot2(sv3, wd.y, Y);
            float rinv = rsqrtf(fmaxf(fmaf(X, X, Y * Y), 1e-30f));
            cs1[img][o * 196 + pos] = packh2(X * rinv, Y * rinv);
        }
    }
    __syncthreads();

    // ---- Stage 2: 4x4/s2 conv, 4->8 ch, 14x14 -> 6x6 ----
    for (int idx = tid; idx < 288; idx += 128) {
        const int o   = idx & 7;
        const int pos = idx >> 3;
        const int i   = pos / 6;
        const int j   = pos - i * 6;
        const unsigned* cbase = &cs1[img][(2 * i) * 14 + 2 * j];
        const uint4*    wbase = &w2t[o * 33];
        float X = 0.f, Y = 0.f;
        #pragma unroll
        for (int c = 0; c < 4; ++c) {
            #pragma unroll
            for (int dy = 0; dy < 4; ++dy) {
                const unsigned* r = cbase + c * 196 + dy * 14;  // 8B aligned
                uint2 va = *(const uint2*)(r);
                uint2 vb = *(const uint2*)(r + 2);
                uint4 wA = wbase[c * 8 + dy * 2 + 0];  // taps dx=0,1
                uint4 wB = wbase[c * 8 + dy * 2 + 1];  // taps dx=2,3
                X = fdot2(va.x, wA.x, X); Y = fdot2(swap16(va.x), wA.y, Y);
                X = fdot2(va.y, wA.z, X); Y = fdot2(swap16(va.y), wA.w, Y);
                X = fdot2(vb.x, wB.x, X); Y = fdot2(swap16(vb.x), wB.y, Y);
                X = fdot2(vb.y, wB.z, X); Y = fdot2(swap16(vb.y), wB.w, Y);
            }
        }
        float rinv = rsqrtf(fmaxf(fmaf(X, X, Y * Y), 1e-30f));
        cs2[img][idx] = packh2(X * rinv, Y * rinv);
    }
    __syncthreads();

    // ---- Stage 3: ring-FF 288 -> 10, out = sin(angle) = Y/r ----
    // tid = n*12 + g: output n, interleaved features f = g + 12k, k<24.
    // Interleaved chunks -> cs2 reads are consecutive words (conflict-free);
    // R2's blocked chunks (stride 48 == 16 mod 32) were 3-way conflicted.
    float2* red = (float2*)cs1[img];   // cs1 free now; 128 float2 scratch
    {
        float X = 0.f, Y = 0.f;
        const int n = tid / 12;
        const int g = tid - n * 12;
        if (n < 10) {
            #pragma unroll 6
            for (int k = 0; k < 24; ++k) {
                const int f = g + 12 * k;
                unsigned v = cs2[img][f];
                uint2 wvv = wt[WT_FF + f * 10 + n];
                X = fdot2(v, wvv.x, X);
                Y = fdot2(swap16(v), wvv.y, Y);
            }
        }
        red[tid] = make_float2(X, Y);
    }
    __syncthreads();
    if (tid < 10) {
        float Xs = 0.f, Ys = 0.f;
        #pragma unroll
        for (int g2 = 0; g2 < 12; ++g2) {
            float2 p = red[tid * 12 + g2];
            Xs += p.x; Ys += p.y;
        }
        float rinv = rsqrtf(fmaxf(fmaf(Xs, Xs, Ys * Ys), 1e-30f));
        out[b * 10 + tid] = Ys * rinv;
    }
}

extern "C" void kernel_launch(void* const* d_in, const int* in_sizes, int n_in,
                              void* d_out, int out_size, void* d_ws, size_t ws_size,
                              hipStream_t stream) {
    const float* x   = (const float*)d_in[0];
    const float* w1  = (const float*)d_in[1];
    const float* w2  = (const float*)d_in[2];
    const float* ffw = (const float*)d_in[3];
    uint2* wt = (uint2*)d_ws;              // needs 3408*8 = 27264 bytes
    float* o  = (float*)d_out;

    ringnn_setup<<<14, 256, 0, stream>>>(w1, w2, ffw, wt);
    ringnn_main<<<2048, 256, 0, stream>>>(x, wt, o);
}

// Round 4
// 86.868 us; speedup vs baseline: 1.8155x; 1.8155x over previous
//
#include <hip/hip_runtime.h>

// d_ws layout: 3408 x uint2 (half4 each): lo = half2(cos,sin) [for X-dot],
//                                         hi = half2(cos,-sin) [for Y-dot]
// [0..15]     conv1 (o*4 + dy*2 + dx)
// [16..527]   conv2 (o*64 + c*16 + dy*4 + dx)
// [528..3407] ff    (f*10 + n)
#define WT_W1 0
#define WT_W2 16
#define WT_FF 528

typedef _Float16 h2 __attribute__((ext_vector_type(2)));

__device__ __forceinline__ float fdot2(unsigned a, unsigned b, float c) {
    return __builtin_amdgcn_fdot2(__builtin_bit_cast(h2, a),
                                  __builtin_bit_cast(h2, b), c, false);
}
__device__ __forceinline__ unsigned swap16(unsigned v) {
    return (v >> 16) | (v << 16);   // v_alignbit_b32
}
__device__ __forceinline__ unsigned packh2(float x, float y) {
    h2 h; h.x = (_Float16)x; h.y = (_Float16)y;
    return __builtin_bit_cast(unsigned, h);
}

__global__ void ringnn_setup(const float* __restrict__ w1,
                             const float* __restrict__ w2,
                             const float* __restrict__ ffw,
                             uint2* __restrict__ wt) {
    int t = blockIdx.x * blockDim.x + threadIdx.x;
    if (t >= 3408) return;
    float a;
    if (t < 16)        a = w1[t];
    else if (t < 528)  a = w2[t - 16];
    else               a = ffw[t - 528];
    float s, c;
    __sincosf(a, &s, &c);
    uint2 v;
    v.x = packh2(c, s);
    v.y = packh2(c, -s);
    wt[t] = v;
}

// 256 threads = 4 waves; 2 images per block, 2 waves (128 lanes) per image.
// NOTE: no min-waves arg in launch_bounds — R3's (256,8) capped the allocator
// at 32 arch VGPRs and spilled ~360 MB/dispatch to scratch (FETCH_SIZE 189 MB).
__global__ __launch_bounds__(256) void ringnn_main(
    const float* __restrict__ x,
    const uint2* __restrict__ wt,
    float* __restrict__ out)
{
    __shared__ uint2 w1t[16];
    // conv2 weights, PADDED: uint4 index = o*33 + c*8 + dy*2 + half
    // o-stride 33 uint4 = 132 words == 4 mod 32 -> the 8 o-groups tile all
    // 32 banks (bank conflict was 52% of cycles in R2 with stride 32;
    // R3 measured SQ_LDS_BANK_CONFLICT == 0 with this layout).
    __shared__ uint4 w2t[264];
    __shared__ unsigned cs1[2][784];        // [img][c*196 + i*14 + j], half2
    __shared__ unsigned cs2[2][288];        // [img][(i*6+j)*8 + o], half2

    const int t   = threadIdx.x;
    const int img = t >> 7;                 // 0..1
    const int tid = t & 127;                // lane within the image's 2 waves
    const int b   = blockIdx.x * 2 + img;
    const float* xb = x + b * 784;

    // ---- Load weight tables into LDS (block-cooperative) ----
    for (int k = t; k < 528; k += 256) {
        uint2 val = wt[k];
        if (k < 16) {
            w1t[k] = val;
        } else {
            int kk = k - 16;
            int o = kk >> 6, rest = kk & 63;
            ((uint2*)w2t)[o * 66 + rest] = val;   // 66 = 33 uint4 per o
        }
    }
    __syncthreads();

    // ---- Stage 1: sincos from global + 2x2/s2 conv, 1->4 ch ----
    for (int pos = tid; pos < 196; pos += 128) {
        const int i = pos / 14;
        const int j = pos - i * 14;
        const float* px = xb + (2 * i) * 28 + 2 * j;
        float2 p0 = *(const float2*)(px);
        float2 p1 = *(const float2*)(px + 28);
        float s0, c0, s1, c1, s2, c2, s3, c3;
        __sincosf(p0.x, &s0, &c0);
        __sincosf(p0.y, &s1, &c1);
        __sincosf(p1.x, &s2, &c2);
        __sincosf(p1.y, &s3, &c3);
        unsigned v0 = packh2(c0, s0), v1 = packh2(c1, s1);
        unsigned v2 = packh2(c2, s2), v3 = packh2(c3, s3);
        unsigned sv0 = swap16(v0), sv1 = swap16(v1);
        unsigned sv2 = swap16(v2), sv3 = swap16(v3);
        #pragma unroll
        for (int o = 0; o < 4; ++o) {
            uint2 wa = w1t[o * 4 + 0], wb = w1t[o * 4 + 1];
            uint2 wc = w1t[o * 4 + 2], wd = w1t[o * 4 + 3];
            float X = 0.f, Y = 0.f;
            X = fdot2(v0, wa.x, X); Y = fdot2(sv0, wa.y, Y);
            X = fdot2(v1, wb.x, X); Y = fdot2(sv1, wb.y, Y);
            X = fdot2(v2, wc.x, X); Y = fdot2(sv2, wc.y, Y);
            X = fdot2(v3, wd.x, X); Y = fdot2(sv3, wd.y, Y);
            float rinv = rsqrtf(fmaxf(fmaf(X, X, Y * Y), 1e-30f));
            cs1[img][o * 196 + pos] = packh2(X * rinv, Y * rinv);
        }
    }
    __syncthreads();

    // ---- Stage 2: 4x4/s2 conv, 4->8 ch, 14x14 -> 6x6 ----
    for (int idx = tid; idx < 288; idx += 128) {
        const int o   = idx & 7;
        const int pos = idx >> 3;
        const int i   = pos / 6;
        const int j   = pos - i * 6;
        const unsigned* cbase = &cs1[img][(2 * i) * 14 + 2 * j];
        const uint4*    wbase = &w2t[o * 33];
        float X = 0.f, Y = 0.f;
        #pragma unroll
        for (int c = 0; c < 4; ++c) {
            #pragma unroll
            for (int dy = 0; dy < 4; ++dy) {
                const unsigned* r = cbase + c * 196 + dy * 14;  // 8B aligned
                uint2 va = *(const uint2*)(r);
                uint2 vb = *(const uint2*)(r + 2);
                uint4 wA = wbase[c * 8 + dy * 2 + 0];  // taps dx=0,1
                uint4 wB = wbase[c * 8 + dy * 2 + 1];  // taps dx=2,3
                X = fdot2(va.x, wA.x, X); Y = fdot2(swap16(va.x), wA.y, Y);
                X = fdot2(va.y, wA.z, X); Y = fdot2(swap16(va.y), wA.w, Y);
                X = fdot2(vb.x, wB.x, X); Y = fdot2(swap16(vb.x), wB.y, Y);
                X = fdot2(vb.y, wB.z, X); Y = fdot2(swap16(vb.y), wB.w, Y);
            }
        }
        float rinv = rsqrtf(fmaxf(fmaf(X, X, Y * Y), 1e-30f));
        cs2[img][idx] = packh2(X * rinv, Y * rinv);
    }
    __syncthreads();

    // ---- Stage 3: ring-FF 288 -> 10, out = sin(angle) = Y/r ----
    // tid = n*12 + g: output n, interleaved features f = g + 12k, k<24.
    // Interleaved chunks -> cs2 reads are consecutive words (conflict-free).
    float2* red = (float2*)cs1[img];   // cs1 free now; 128 float2 scratch
    {
        float X = 0.f, Y = 0.f;
        const int n = tid / 12;
        const int g = tid - n * 12;
        if (n < 10) {
            #pragma unroll 6
            for (int k = 0; k < 24; ++k) {
                const int f = g + 12 * k;
                unsigned v = cs2[img][f];
                uint2 wvv = wt[WT_FF + f * 10 + n];
                X = fdot2(v, wvv.x, X);
                Y = fdot2(swap16(v), wvv.y, Y);
            }
        }
        red[tid] = make_float2(X, Y);
    }
    __syncthreads();
    if (tid < 10) {
        float Xs = 0.f, Ys = 0.f;
        #pragma unroll
        for (int g2 = 0; g2 < 12; ++g2) {
            float2 p = red[tid * 12 + g2];
            Xs += p.x; Ys += p.y;
        }
        float rinv = rsqrtf(fmaxf(fmaf(Xs, Xs, Ys * Ys), 1e-30f));
        out[b * 10 + tid] = Ys * rinv;
    }
}

extern "C" void kernel_launch(void* const* d_in, const int* in_sizes, int n_in,
                              void* d_out, int out_size, void* d_ws, size_t ws_size,
                              hipStream_t stream) {
    const float* x   = (const float*)d_in[0];
    const float* w1  = (const float*)d_in[1];
    const float* w2  = (const float*)d_in[2];
    const float* ffw = (const float*)d_in[3];
    uint2* wt = (uint2*)d_ws;              // needs 3408*8 = 27264 bytes
    float* o  = (float*)d_out;

    ringnn_setup<<<14, 256, 0, stream>>>(w1, w2, ffw, wt);
    ringnn_main<<<2048, 256, 0, stream>>>(x, wt, o);
}

// Round 5
// 84.248 us; speedup vs baseline: 1.8720x; 1.0311x over previous
//
#include <hip/hip_runtime.h>

// d_ws layout: 3408 x uint2 (half4 each): lo = half2(cos,  sin) [X-dot]
//                                         hi = half2(-sin, cos) [Y-dot]
// (Y repack removes every swap16: Y = s*wc - c*ws = dot2((c,s),(-ws,wc)),
//  same activation operand as X. R4 profile: swaps were ~30% of VALU ops.)
// [0..15]     conv1 (o*4 + dy*2 + dx)
// [16..527]   conv2 (o*64 + c*16 + dy*4 + dx)
// [528..3407] ff    (f*10 + n)
#define WT_W1 0
#define WT_W2 16
#define WT_FF 528

typedef _Float16 h2 __attribute__((ext_vector_type(2)));

__device__ __forceinline__ float fdot2(unsigned a, unsigned b, float c) {
    return __builtin_amdgcn_fdot2(__builtin_bit_cast(h2, a),
                                  __builtin_bit_cast(h2, b), c, false);
}
__device__ __forceinline__ unsigned packh2(float x, float y) {
    h2 h; h.x = (_Float16)x; h.y = (_Float16)y;
    return __builtin_bit_cast(unsigned, h);
}

__global__ void ringnn_setup(const float* __restrict__ w1,
                             const float* __restrict__ w2,
                             const float* __restrict__ ffw,
                             uint2* __restrict__ wt) {
    int t = blockIdx.x * blockDim.x + threadIdx.x;
    if (t >= 3408) return;
    float a;
    if (t < 16)        a = w1[t];
    else if (t < 528)  a = w2[t - 16];
    else               a = ffw[t - 528];
    float s, c;
    __sincosf(a, &s, &c);
    uint2 v;
    v.x = packh2(c, s);     // X-dot operand
    v.y = packh2(-s, c);    // Y-dot operand (swap-free form)
    wt[t] = v;
}

// 256 threads = 4 waves; 2 images per block, 2 waves (128 lanes) per image.
// NOTE: plain __launch_bounds__(256) — R3's (256,8) capped the allocator at
// 32 arch VGPRs and spilled ~360 MB/dispatch to scratch.
__global__ __launch_bounds__(256) void ringnn_main(
    const float* __restrict__ x,
    const uint2* __restrict__ wt,
    float* __restrict__ out)
{
    __shared__ uint2 w1t[16];
    // conv2 weights, PADDED: uint4 index = o*33 + c*8 + dy*2 + half
    // o-stride 33 uint4 = 132 words == 4 mod 32 -> the 8 o-groups tile all
    // 32 banks (R2's stride-32 layout cost 52% of cycles in conflicts;
    // this layout measured SQ_LDS_BANK_CONFLICT == 0).
    __shared__ uint4 w2t[264];
    __shared__ unsigned cs1[2][784];        // [img][c*196 + i*14 + j], half2
    __shared__ unsigned cs2[2][288];        // [img][(i*6+j)*8 + o], half2

    const int t   = threadIdx.x;
    const int img = t >> 7;                 // 0..1
    const int tid = t & 127;                // lane within the image's 2 waves
    const int b   = blockIdx.x * 2 + img;
    const float* xb = x + b * 784;

    // ---- Load weight tables into LDS (block-cooperative) ----
    for (int k = t; k < 528; k += 256) {
        uint2 val = wt[k];
        if (k < 16) {
            w1t[k] = val;
        } else {
            int kk = k - 16;
            int o = kk >> 6, rest = kk & 63;
            ((uint2*)w2t)[o * 66 + rest] = val;   // 66 = 33 uint4 per o
        }
    }
    __syncthreads();

    // ---- Stage 1: sincos from global + 2x2/s2 conv, 1->4 ch ----
    for (int pos = tid; pos < 196; pos += 128) {
        const int i = pos / 14;
        const int j = pos - i * 14;
        const float* px = xb + (2 * i) * 28 + 2 * j;
        float2 p0 = *(const float2*)(px);
        float2 p1 = *(const float2*)(px + 28);
        float s0, c0, s1, c1, s2, c2, s3, c3;
        __sincosf(p0.x, &s0, &c0);
        __sincosf(p0.y, &s1, &c1);
        __sincosf(p1.x, &s2, &c2);
        __sincosf(p1.y, &s3, &c3);
        unsigned v0 = packh2(c0, s0), v1 = packh2(c1, s1);
        unsigned v2 = packh2(c2, s2), v3 = packh2(c3, s3);
        #pragma unroll
        for (int o = 0; o < 4; ++o) {
            uint2 wa = w1t[o * 4 + 0], wb = w1t[o * 4 + 1];
            uint2 wc = w1t[o * 4 + 2], wd = w1t[o * 4 + 3];
            float X = 0.f, Y = 0.f;
            X = fdot2(v0, wa.x, X); Y = fdot2(v0, wa.y, Y);
            X = fdot2(v1, wb.x, X); Y = fdot2(v1, wb.y, Y);
            X = fdot2(v2, wc.x, X); Y = fdot2(v2, wc.y, Y);
            X = fdot2(v3, wd.x, X); Y = fdot2(v3, wd.y, Y);
            float rinv = rsqrtf(fmaxf(fmaf(X, X, Y * Y), 1e-30f));
            cs1[img][o * 196 + pos] = packh2(X * rinv, Y * rinv);
        }
    }
    __syncthreads();

    // ---- Stage 2: 4x4/s2 conv, 4->8 ch, 14x14 -> 6x6 ----
    for (int idx = tid; idx < 288; idx += 128) {
        const int o   = idx & 7;
        const int pos = idx >> 3;
        const int i   = pos / 6;
        const int j   = pos - i * 6;
        const unsigned* cbase = &cs1[img][(2 * i) * 14 + 2 * j];
        const uint4*    wbase = &w2t[o * 33];
        // Split accumulators (c-pairs) halve the serial fdot2 chain depth.
        float X0 = 0.f, Y0 = 0.f, X1 = 0.f, Y1 = 0.f;
        #pragma unroll
        for (int c = 0; c < 4; ++c) {
            float Xa = 0.f, Ya = 0.f;
            #pragma unroll
            for (int dy = 0; dy < 4; ++dy) {
                const unsigned* r = cbase + c * 196 + dy * 14;  // 8B aligned
                uint2 va = *(const uint2*)(r);
                uint2 vb = *(const uint2*)(r + 2);
                uint4 wA = wbase[c * 8 + dy * 2 + 0];  // taps dx=0,1
                uint4 wB = wbase[c * 8 + dy * 2 + 1];  // taps dx=2,3
                Xa = fdot2(va.x, wA.x, Xa); Ya = fdot2(va.x, wA.y, Ya);
                Xa = fdot2(va.y, wA.z, Xa); Ya = fdot2(va.y, wA.w, Ya);
                Xa = fdot2(vb.x, wB.x, Xa); Ya = fdot2(vb.x, wB.y, Ya);
                Xa = fdot2(vb.y, wB.z, Xa); Ya = fdot2(vb.y, wB.w, Ya);
            }
            if (c & 1) { X1 += Xa; Y1 += Ya; } else { X0 += Xa; Y0 += Ya; }
        }
        float X = X0 + X1, Y = Y0 + Y1;
        float rinv = rsqrtf(fmaxf(fmaf(X, X, Y * Y), 1e-30f));
        cs2[img][idx] = packh2(X * rinv, Y * rinv);
    }
    __syncthreads();

    // ---- Stage 3: ring-FF 288 -> 10, out = sin(angle) = Y/r ----
    // tid = n*12 + g: output n, interleaved features f = g + 12k, k<24.
    // Interleaved chunks -> cs2 reads are consecutive words (conflict-free).
    float2* red = (float2*)cs1[img];   // cs1 free now; 128 float2 scratch
    {
        float X = 0.f, Y = 0.f;
        const int n = tid / 12;
        const int g = tid - n * 12;
        if (n < 10) {
            #pragma unroll 6
            for (int k = 0; k < 24; ++k) {
                const int f = g + 12 * k;
                unsigned v = cs2[img][f];
                uint2 wvv = wt[WT_FF + f * 10 + n];
                X = fdot2(v, wvv.x, X);
                Y = fdot2(v, wvv.y, Y);
            }
        }
        red[tid] = make_float2(X, Y);
    }
    __syncthreads();
    if (tid < 10) {
        float Xs = 0.f, Ys = 0.f;
        #pragma unroll
        for (int g2 = 0; g2 < 12; ++g2) {
            float2 p = red[tid * 12 + g2];
            Xs += p.x; Ys += p.y;
        }
        float rinv = rsqrtf(fmaxf(fmaf(Xs, Xs, Ys * Ys), 1e-30f));
        out[b * 10 + tid] = Ys * rinv;
    }
}

extern "C" void kernel_launch(void* const* d_in, const int* in_sizes, int n_in,
                              void* d_out, int out_size, void* d_ws, size_t ws_size,
                              hipStream_t stream) {
    const float* x   = (const float*)d_in[0];
    const float* w1  = (const float*)d_in[1];
    const float* w2  = (const float*)d_in[2];
    const float* ffw = (const float*)d_in[3];
    uint2* wt = (uint2*)d_ws;              // needs 3408*8 = 27264 bytes
    float* o  = (float*)d_out;

    ringnn_setup<<<14, 256, 0, stream>>>(w1, w2, ffw, wt);
    ringnn_main<<<2048, 256, 0, stream>>>(x, wt, o);
}

// Round 6
// 82.222 us; speedup vs baseline: 1.9181x; 1.0246x over previous
//
#include <hip/hip_runtime.h>

// d_ws layout: 3408 x uint2 (half4 each): lo = half2(cos,  sin) [X-dot]
//                                         hi = half2(-sin, cos) [Y-dot]
// (Y = s*wc - c*ws = dot2((c,s),(-ws,wc)) — swap-free form.)
// [0..15]     conv1 (o*4 + dy*2 + dx)
// [16..527]   conv2 (o*64 + c*16 + dy*4 + dx)
// [528..3407] ff    (f*10 + n)
#define WT_W1 0
#define WT_W2 16
#define WT_FF 528

typedef _Float16 h2 __attribute__((ext_vector_type(2)));

__device__ __forceinline__ float fdot2(unsigned a, unsigned b, float c) {
    return __builtin_amdgcn_fdot2(__builtin_bit_cast(h2, a),
                                  __builtin_bit_cast(h2, b), c, false);
}
__device__ __forceinline__ unsigned packh2(float x, float y) {
    h2 h; h.x = (_Float16)x; h.y = (_Float16)y;
    return __builtin_bit_cast(unsigned, h);
}

__global__ void ringnn_setup(const float* __restrict__ w1,
                             const float* __restrict__ w2,
                             const float* __restrict__ ffw,
                             uint2* __restrict__ wt) {
    int t = blockIdx.x * blockDim.x + threadIdx.x;
    if (t >= 3408) return;
    float a;
    if (t < 16)        a = w1[t];
    else if (t < 528)  a = w2[t - 16];
    else               a = ffw[t - 528];
    float s, c;
    __sincosf(a, &s, &c);
    uint2 v;
    v.x = packh2(c, s);     // X-dot operand
    v.y = packh2(-s, c);    // Y-dot operand
    wt[t] = v;
}

// 256 threads = 4 waves; 2 images per block.
// Stage 1/3: 2 waves (128 lanes) per image.
// Stage 2:   wave = (img, o-half); lane = output position (36 active);
//            weight reads are WAVE-UNIFORM -> scalar s_load path, off LDS.
// NOTE: plain __launch_bounds__(256) — (256,8) caused catastrophic spill (R3).
__global__ __launch_bounds__(256) void ringnn_main(
    const float* __restrict__ x,
    const uint2* __restrict__ wt,
    float* __restrict__ out)
{
    __shared__ unsigned cs1[2][784];        // [img][c*196 + i*14 + j], half2
    __shared__ unsigned cs2[2][288];        // [img][(i*6+j)*8 + o], half2

    const int t    = threadIdx.x;
    const int img  = t >> 7;                // 0..1 (stages 1,3)
    const int tid  = t & 127;               // lane within the image's 2 waves
    const int b    = blockIdx.x * 2 + img;
    const float* xb = x + b * 784;

    // ---- Stage 1: sincos from global + 2x2/s2 conv, 1->4 ch ----
    // conv1 weight indices are compile-time uniform -> s_load (const cache).
    for (int pos = tid; pos < 196; pos += 128) {
        const int i = pos / 14;
        const int j = pos - i * 14;
        const float* px = xb + (2 * i) * 28 + 2 * j;
        float2 p0 = *(const float2*)(px);
        float2 p1 = *(const float2*)(px + 28);
        float s0, c0, s1, c1, s2, c2, s3, c3;
        __sincosf(p0.x, &s0, &c0);
        __sincosf(p0.y, &s1, &c1);
        __sincosf(p1.x, &s2, &c2);
        __sincosf(p1.y, &s3, &c3);
        unsigned v0 = packh2(c0, s0), v1 = packh2(c1, s1);
        unsigned v2 = packh2(c2, s2), v3 = packh2(c3, s3);
        #pragma unroll
        for (int o = 0; o < 4; ++o) {
            uint2 wa = wt[WT_W1 + o * 4 + 0], wb = wt[WT_W1 + o * 4 + 1];
            uint2 wc = wt[WT_W1 + o * 4 + 2], wd = wt[WT_W1 + o * 4 + 3];
            float X = 0.f, Y = 0.f;
            X = fdot2(v0, wa.x, X); Y = fdot2(v0, wa.y, Y);
            X = fdot2(v1, wb.x, X); Y = fdot2(v1, wb.y, Y);
            X = fdot2(v2, wc.x, X); Y = fdot2(v2, wc.y, Y);
            X = fdot2(v3, wd.x, X); Y = fdot2(v3, wd.y, Y);
            float rinv = rsqrtf(fmaxf(fmaf(X, X, Y * Y), 1e-30f));
            cs1[img][o * 196 + pos] = packh2(X * rinv, Y * rinv);
        }
    }
    __syncthreads();

    // ---- Stage 2: 4x4/s2 conv, 4->8 ch, 14x14 -> 6x6 ----
    {
        const int wave  = t >> 6;                               // 0..3
        const int lane  = t & 63;
        const int img2  = wave >> 1;
        // o-half is wave-uniform; readfirstlane forces SGPR so every weight
        // address below is provably uniform -> s_load, zero LDS traffic.
        const int ohalf = __builtin_amdgcn_readfirstlane(wave & 1);
        if (lane < 36) {
            const int i = lane / 6;
            const int j = lane - i * 6;
            const unsigned* cb = &cs1[img2][(2 * i) * 14 + 2 * j];
            float X[4] = {0.f, 0.f, 0.f, 0.f};
            float Y[4] = {0.f, 0.f, 0.f, 0.f};
            #pragma unroll
            for (int c = 0; c < 4; ++c) {
                // register-cache the 16 activation taps for this channel
                uint2 a[4][2];
                #pragma unroll
                for (int dy = 0; dy < 4; ++dy) {
                    const unsigned* r = cb + c * 196 + dy * 14;  // 8B aligned
                    a[dy][0] = *(const uint2*)(r);
                    a[dy][1] = *(const uint2*)(r + 2);
                }
                #pragma unroll
                for (int oo = 0; oo < 4; ++oo) {
                    const uint2* wp = wt + WT_W2 + (ohalf * 4 + oo) * 64 + c * 16;
                    #pragma unroll
                    for (int dy = 0; dy < 4; ++dy) {
                        uint2 w0 = wp[dy * 4 + 0], w1_ = wp[dy * 4 + 1];
                        uint2 w2_ = wp[dy * 4 + 2], w3 = wp[dy * 4 + 3];
                        unsigned va = a[dy][0].x, vb = a[dy][0].y;
                        unsigned vc = a[dy][1].x, vd = a[dy][1].y;
                        X[oo] = fdot2(va, w0.x, X[oo]); Y[oo] = fdot2(va, w0.y, Y[oo]);
                        X[oo] = fdot2(vb, w1_.x, X[oo]); Y[oo] = fdot2(vb, w1_.y, Y[oo]);
                        X[oo] = fdot2(vc, w2_.x, X[oo]); Y[oo] = fdot2(vc, w2_.y, Y[oo]);
                        X[oo] = fdot2(vd, w3.x, X[oo]); Y[oo] = fdot2(vd, w3.y, Y[oo]);
                    }
                }
            }
            // normalize and store 4 outputs as 2x b64 (word idx multiple of 4)
            unsigned r0, r1, r2, r3;
            {
                float rv0 = rsqrtf(fmaxf(fmaf(X[0], X[0], Y[0] * Y[0]), 1e-30f));
                float rv1 = rsqrtf(fmaxf(fmaf(X[1], X[1], Y[1] * Y[1]), 1e-30f));
                float rv2 = rsqrtf(fmaxf(fmaf(X[2], X[2], Y[2] * Y[2]), 1e-30f));
                float rv3 = rsqrtf(fmaxf(fmaf(X[3], X[3], Y[3] * Y[3]), 1e-30f));
                r0 = packh2(X[0] * rv0, Y[0] * rv0);
                r1 = packh2(X[1] * rv1, Y[1] * rv1);
                r2 = packh2(X[2] * rv2, Y[2] * rv2);
                r3 = packh2(X[3] * rv3, Y[3] * rv3);
            }
            uint2* dst = (uint2*)&cs2[img2][lane * 8 + ohalf * 4];
            dst[0] = make_uint2(r0, r1);
            dst[1] = make_uint2(r2, r3);
        }
    }
    __syncthreads();

    // ---- Stage 3: ring-FF 288 -> 10, out = sin(angle) = Y/r ----
    // tid = n*12 + g: output n, interleaved features f = g + 12k, k<24.
    float2* red = (float2*)cs1[img];   // cs1 free now; 128 float2 scratch
    {
        float X = 0.f, Y = 0.f;
        const int n = tid / 12;
        const int g = tid - n * 12;
        if (n < 10) {
            #pragma unroll 6
            for (int k = 0; k < 24; ++k) {
                const int f = g + 12 * k;
                unsigned v = cs2[img][f];
                uint2 wvv = wt[WT_FF + f * 10 + n];
                X = fdot2(v, wvv.x, X);
                Y = fdot2(v, wvv.y, Y);
            }
        }
        red[tid] = make_float2(X, Y);
    }
    __syncthreads();
    if (tid < 10) {
        float Xs = 0.f, Ys = 0.f;
        #pragma unroll
        for (int g2 = 0; g2 < 12; ++g2) {
            float2 p = red[tid * 12 + g2];
            Xs += p.x; Ys += p.y;
        }
        float rinv = rsqrtf(fmaxf(fmaf(Xs, Xs, Ys * Ys), 1e-30f));
        out[b * 10 + tid] = Ys * rinv;
    }
}

extern "C" void kernel_launch(void* const* d_in, const int* in_sizes, int n_in,
                              void* d_out, int out_size, void* d_ws, size_t ws_size,
                              hipStream_t stream) {
    const float* x   = (const float*)d_in[0];
    const float* w1  = (const float*)d_in[1];
    const float* w2  = (const float*)d_in[2];
    const float* ffw = (const float*)d_in[3];
    uint2* wt = (uint2*)d_ws;              // needs 3408*8 = 27264 bytes
    float* o  = (float*)d_out;

    ringnn_setup<<<14, 256, 0, stream>>>(w1, w2, ffw, wt);
    ringnn_main<<<2048, 256, 0, stream>>>(x, wt, o);
}